// Round 21
// baseline (60.343 us; speedup 1.0000x reference)
//
#include <hip/hip_runtime.h>
#include <hip/hip_fp16.h>
#include <hip/hip_bf16.h>

// SAM self-attention. bs=8, C=64, Dqk=32, HW=4096. Inputs f32, output f32.
// KV-split-2 flash attention; no LDS / no barriers; pre-fragmented Kf/Vf.
// r21: BRANCH-FREE softmax. Row max frozen from tile 0 (prologue); P and V
// are bf16 (f32 exponent range -> no overflow without rescale), so the KV
// loop has no max-reduce / ballot / branch -> compiler can pipeline freely.
// QK^T stays fp16 (precision where it matters). Q/K fp16, P/V bf16.

typedef short          f16x8 __attribute__((ext_vector_type(8)));
typedef float          f32x4 __attribute__((ext_vector_type(4)));
typedef unsigned short u16;
typedef unsigned int   u32;

#define HW  4096
#define CC  64
#define DQK 32
#define NBLK2 256     // 8 batches * 32 q-blocks (128 q each)

__device__ __forceinline__ u16 f2h(float f) {
    __half h = __float2half(f);
    return *reinterpret_cast<u16*>(&h);
}
__device__ __forceinline__ u16 f2bf(float f) {
    __hip_bfloat16 h = __float2bfloat16(f);
    return *reinterpret_cast<u16*>(&h);
}
__device__ __forceinline__ float h2f(u16 u) {
    __half h; __builtin_memcpy(&h, &u, 2); return __half2float(h);
}
__device__ __forceinline__ float ex2(float x) {
    return __builtin_amdgcn_exp2f(x);
}
__device__ __forceinline__ float max16(const f32x4* s) {
    float a = fmaxf(fmaxf(s[0][0], s[0][1]), s[0][2]);
    a = fmaxf(fmaxf(a, s[0][3]), s[1][0]);
    a = fmaxf(fmaxf(a, s[1][1]), s[1][2]);
    a = fmaxf(fmaxf(a, s[1][3]), s[2][0]);
    a = fmaxf(fmaxf(a, s[2][1]), s[2][2]);
    a = fmaxf(fmaxf(a, s[2][3]), s[3][0]);
    a = fmaxf(fmaxf(a, s[3][1]), s[3][2]);
    return fmaxf(a, s[3][3]);
}

// ---------------------------------------------------------------------------
// Projection. Q -> Qr[n][32] fp16; K -> Kf pre-fragmented fp16;
// V -> Vf pre-fragmented BF16 via SWAPPED mfma (D[m][c]) -> uint2 stores.
// wq pre-scaled by log2(e) -> exp2-domain scores.
// ---------------------------------------------------------------------------
__global__ __launch_bounds__(256) void proj_kernel(
    const float* __restrict__ x,  const float* __restrict__ wq,
    const float* __restrict__ wk, const float* __restrict__ wv,
    u16* __restrict__ Qr, u16* __restrict__ Kf, u16* __restrict__ Vf)
{
    const int b    = blockIdx.x;
    const int tile = blockIdx.y;          // 64-column chunk index
    const int n0   = tile * 64;
    const int tid  = threadIdx.x;

    __shared__ __align__(16) u16 Xt[64][88];   // X^T tile [n][c], fp16

    {
        const int c  = tid >> 2;
        const int nc = (tid & 3) * 16;
        const float* src = x + ((size_t)(b * CC + c) * HW + n0 + nc);
        float fv[16];
        *(f32x4*)(fv)      = *(const f32x4*)(src);
        *(f32x4*)(fv + 4)  = *(const f32x4*)(src + 4);
        *(f32x4*)(fv + 8)  = *(const f32x4*)(src + 8);
        *(f32x4*)(fv + 12) = *(const f32x4*)(src + 12);
        #pragma unroll
        for (int i = 0; i < 16; ++i) Xt[nc + i][c] = f2h(fv[i]);
    }
    __syncthreads();

    const int wave = tid >> 6;
    const int lane = tid & 63;
    const int lr   = lane & 15;
    const int lg   = lane >> 4;
    const int lk   = lg * 8;

    const float* W = (wave == 0) ? wq : (wave == 1) ? wk
                   : (wave == 2) ? wv : (wv + 32 * 64);
    const float scale = (wave == 0) ? 1.4426950408889634f : 1.0f;   // log2(e)

    f16x8 a[2][2];
    #pragma unroll
    for (int dt = 0; dt < 2; ++dt)
        #pragma unroll
        for (int h = 0; h < 2; ++h) {
            const float* p = W + (dt * 16 + lr) * 64 + h * 32 + lk;
            f32x4 lo = *(const f32x4*)p, hi = *(const f32x4*)(p + 4);
            u16 t[8];
            #pragma unroll
            for (int j = 0; j < 4; ++j) {
                t[j]     = f2h(lo[j] * scale);
                t[4 + j] = f2h(hi[j] * scale);
            }
            a[dt][h] = *(const f16x8*)t;
        }

    const f32x4 fz = {0.f, 0.f, 0.f, 0.f};
    f32x4 acc[2][4];
    #pragma unroll
    for (int dt = 0; dt < 2; ++dt)
        #pragma unroll
        for (int nt = 0; nt < 4; ++nt) acc[dt][nt] = fz;

    if (wave < 2) {
        // D[d][n]: col(lr)=n', row(4lg+r)=d'
        #pragma unroll
        for (int nt = 0; nt < 4; ++nt)
            #pragma unroll
            for (int h = 0; h < 2; ++h) {
                f16x8 bx = *(const f16x8*)(&Xt[nt * 16 + lr][h * 32 + lk]);
                #pragma unroll
                for (int dt = 0; dt < 2; ++dt)
                    acc[dt][nt] = __builtin_amdgcn_mfma_f32_16x16x32_f16(
                                      a[dt][h], bx, acc[dt][nt], 0, 0, 0);
            }
        if (wave == 0) {
            #pragma unroll
            for (int dt = 0; dt < 2; ++dt)
                #pragma unroll
                for (int nt = 0; nt < 4; ++nt) {
                    const int n = n0 + nt * 16 + lr;
                    const int d = dt * 16 + lg * 4;
                    u16 pkk[4];
                    #pragma unroll
                    for (int r = 0; r < 4; ++r) pkk[r] = f2h(acc[dt][nt][r]);
                    *(uint2*)(Qr + ((size_t)(b * HW + n) * DQK + d)) = *(uint2*)pkk;
                }
        } else {
            // K -> Kf: element (m_in, d) at [mt][lgk=d>>3][lrk][j=d&7]
            #pragma unroll
            for (int dt = 0; dt < 2; ++dt)
                #pragma unroll
                for (int nt = 0; nt < 4; ++nt) {
                    const int m_in = nt * 16 + lr;
                    const int mt   = 2 * (m_in >> 5) + ((m_in >> 2) & 1);
                    const int lrk  = ((m_in >> 4) & 1) * 8 + ((m_in >> 3) & 1) * 4 + (m_in & 3);
                    const int lgk  = dt * 2 + (lg >> 1);
                    const int j0   = (lg & 1) * 4;
                    u16 pkk[4];
                    #pragma unroll
                    for (int r = 0; r < 4; ++r) pkk[r] = f2h(acc[dt][nt][r]);
                    *(uint2*)(Kf + (size_t)(b * 64 + tile) * 2048
                                 + mt * 512 + lgk * 128 + lrk * 8 + j0) = *(uint2*)pkk;
                }
        }
    } else {
        // V waves: SWAPPED mfma -> D[m][c]: col(lr)=c', row(4lg+r)=m'. BF16 out.
        #pragma unroll
        for (int nt = 0; nt < 4; ++nt)
            #pragma unroll
            for (int h = 0; h < 2; ++h) {
                f16x8 bx = *(const f16x8*)(&Xt[nt * 16 + lr][h * 32 + lk]);
                #pragma unroll
                for (int dt = 0; dt < 2; ++dt)
                    acc[dt][nt] = __builtin_amdgcn_mfma_f32_16x16x32_f16(
                                      bx, a[dt][h], acc[dt][nt], 0, 0, 0);
            }
        const int cbase = (wave - 2) * 32;
        #pragma unroll
        for (int dt = 0; dt < 2; ++dt)
            #pragma unroll
            for (int nt = 0; nt < 4; ++nt) {
                const int c   = cbase + dt * 16 + lr;
                const int ct  = c >> 4, lrv = c & 15;
                const int m0  = nt * 16 + 4 * lg;          // r = 0..3 consecutive
                const int h   = m0 >> 5;
                const int lgv = (m0 >> 3) & 3;
                const int j0  = m0 & 7;                    // (lg&1)*4
                u16 pkk[4];
                #pragma unroll
                for (int r = 0; r < 4; ++r) pkk[r] = f2bf(acc[dt][nt][r]);
                *(uint2*)(Vf + (size_t)(b * 64 + tile) * 4096
                             + ct * 1024 + h * 512 + lgv * 128 + lrv * 8 + j0)
                    = *(uint2*)pkk;
            }
    }
}

// ---------------------------------------------------------------------------
// Flash attention, KV-split S ways. Block = 128 q (4 independent waves x 32).
// Prologue freezes row max m from tile 0; KV loop is BRANCH-FREE:
// QK fp16 MFMA (C=0) -> P = 2^(s-m) in bf16 -> lrow/PV bf16 MFMAs.
// ---------------------------------------------------------------------------
template<int S>
__global__ __launch_bounds__(256, 4) void attn_kernel(
    const u16* __restrict__ Qr, const u16* __restrict__ Kf,
    const u16* __restrict__ Vf, float* __restrict__ out,
    u16* __restrict__ Opart, float* __restrict__ Ml)
{
    constexpr int NT = HW / S / 64;
    const int b    = blockIdx.x;
    const int nb   = blockIdx.y;
    const int sp   = blockIdx.z;
    const int tid  = threadIdx.x;
    const int wave = tid >> 6;
    const int lane = tid & 63;
    const int lr   = lane & 15;
    const int lg   = lane >> 4;
    const int lk   = lg * 8;

    const int qb = nb * 128 + wave * 32;
    const f16x8 aq0 = *(const f16x8*)(Qr + (size_t)(b * HW + qb + lr) * DQK + lk);
    const f16x8 aq1 = *(const f16x8*)(Qr + (size_t)(b * HW + qb + 16 + lr) * DQK + lk);

    const f16x8 ones_bf = { 0x3F80, 0x3F80, 0x3F80, 0x3F80,
                            0x3F80, 0x3F80, 0x3F80, 0x3F80 };   // bf16 1.0
    const f32x4 fz = {0.f, 0.f, 0.f, 0.f};

    const int tile0 = sp * NT;
    const u16* KfT = Kf + (size_t)(b * 64 + tile0) * 2048 + lg * 128 + lr * 8;
    const u16* VfT = Vf + (size_t)(b * 64 + tile0) * 4096 + lg * 128 + lr * 8;

    f16x8 kf[4], vf[4][2];
    #pragma unroll
    for (int mt = 0; mt < 4; ++mt)
        kf[mt] = *(const f16x8*)(KfT + mt * 512);
    #pragma unroll
    for (int ct = 0; ct < 4; ++ct)
        #pragma unroll
        for (int h = 0; h < 2; ++h)
            vf[ct][h] = *(const f16x8*)(VfT + ct * 1024 + h * 512);

    // ---- prologue: freeze row max from tile 0 (one-time) ----
    float mrow[2];
    {
        f32x4 s0[4], s1[4];
        #pragma unroll
        for (int mt = 0; mt < 4; ++mt) {
            s0[mt] = __builtin_amdgcn_mfma_f32_16x16x32_f16(kf[mt], aq0, fz, 0, 0, 0);
            s1[mt] = __builtin_amdgcn_mfma_f32_16x16x32_f16(kf[mt], aq1, fz, 0, 0, 0);
        }
        float v0 = max16(s0), v1 = max16(s1);
        v0 = fmaxf(v0, __shfl_xor(v0, 16, 64));
        v0 = fmaxf(v0, __shfl_xor(v0, 32, 64));
        v1 = fmaxf(v1, __shfl_xor(v1, 16, 64));
        v1 = fmaxf(v1, __shfl_xor(v1, 32, 64));
        mrow[0] = v0;            // q = lr (s-layout); uniform per row group
        mrow[1] = v1;
    }

    f32x4 o[2][4];
    #pragma unroll
    for (int qs = 0; qs < 2; ++qs)
        #pragma unroll
        for (int ct = 0; ct < 4; ++ct) o[qs][ct] = fz;
    f32x4 lrow[2] = {fz, fz};                 // q = 4*lg + r (o-layout)

    #pragma unroll 2
    for (int t = 0; t < NT; ++t) {
        const int tn = (t + 1 < NT) ? t + 1 : t;

        // ================= qs = 0 =================
        f32x4 s[4];
        #pragma unroll
        for (int mt = 0; mt < 4; ++mt)
            s[mt] = __builtin_amdgcn_mfma_f32_16x16x32_f16(kf[mt], aq0, fz, 0, 0, 0);

        f16x8 pa0[2];
        {
            const float m = mrow[0];
            #pragma unroll
            for (int h = 0; h < 2; ++h) {
                u16 t8[8];
                #pragma unroll
                for (int half = 0; half < 2; ++half)
                    #pragma unroll
                    for (int r = 0; r < 4; ++r)
                        t8[half * 4 + r] = f2bf(ex2(s[2*h + half][r] - m));
                __builtin_memcpy(&pa0[h], t8, 16);
            }
        }
        {
            f32x4 rs = __builtin_amdgcn_mfma_f32_16x16x32_bf16(pa0[0], ones_bf, fz, 0, 0, 0);
            rs = __builtin_amdgcn_mfma_f32_16x16x32_bf16(pa0[1], ones_bf, rs, 0, 0, 0);
            #pragma unroll
            for (int r = 0; r < 4; ++r) lrow[0][r] += rs[r];
        }
        #pragma unroll
        for (int ct = 0; ct < 4; ++ct) {
            o[0][ct] = __builtin_amdgcn_mfma_f32_16x16x32_bf16(pa0[0], vf[ct][0], o[0][ct], 0, 0, 0);
            o[0][ct] = __builtin_amdgcn_mfma_f32_16x16x32_bf16(pa0[1], vf[ct][1], o[0][ct], 0, 0, 0);
        }

        // ================= qs = 1 =================
        #pragma unroll
        for (int mt = 0; mt < 4; ++mt)
            s[mt] = __builtin_amdgcn_mfma_f32_16x16x32_f16(kf[mt], aq1, fz, 0, 0, 0);

        // kf consumed -> reload for next tile
        #pragma unroll
        for (int mt = 0; mt < 4; ++mt)
            kf[mt] = *(const f16x8*)(KfT + (size_t)tn * 2048 + mt * 512);

        f16x8 pa1[2];
        {
            const float m = mrow[1];
            #pragma unroll
            for (int h = 0; h < 2; ++h) {
                u16 t8[8];
                #pragma unroll
                for (int half = 0; half < 2; ++half)
                    #pragma unroll
                    for (int r = 0; r < 4; ++r)
                        t8[half * 4 + r] = f2bf(ex2(s[2*h + half][r] - m));
                __builtin_memcpy(&pa1[h], t8, 16);
            }
        }
        {
            f32x4 rs = __builtin_amdgcn_mfma_f32_16x16x32_bf16(pa1[0], ones_bf, fz, 0, 0, 0);
            rs = __builtin_amdgcn_mfma_f32_16x16x32_bf16(pa1[1], ones_bf, rs, 0, 0, 0);
            #pragma unroll
            for (int r = 0; r < 4; ++r) lrow[1][r] += rs[r];
        }
        #pragma unroll
        for (int ct = 0; ct < 4; ++ct) {
            o[1][ct] = __builtin_amdgcn_mfma_f32_16x16x32_bf16(pa1[0], vf[ct][0], o[1][ct], 0, 0, 0);
            o[1][ct] = __builtin_amdgcn_mfma_f32_16x16x32_bf16(pa1[1], vf[ct][1], o[1][ct], 0, 0, 0);
        }

        // vf consumed -> reload for next tile
        #pragma unroll
        for (int ct = 0; ct < 4; ++ct)
            #pragma unroll
            for (int h = 0; h < 2; ++h)
                vf[ct][h] = *(const f16x8*)(VfT + (size_t)tn * 4096 + ct * 1024 + h * 512);
    }

    if constexpr (S == 1) {
        #pragma unroll
        for (int qs = 0; qs < 2; ++qs)
            #pragma unroll
            for (int ct = 0; ct < 4; ++ct) {
                const int c = ct * 16 + lr;
                f32x4 st;
                #pragma unroll
                for (int r = 0; r < 4; ++r) st[r] = o[qs][ct][r] / lrow[qs][r];
                *(f32x4*)(out + (size_t)(b * CC + c) * HW + qb + qs * 16 + lg * 4) = st;
            }
    } else {
        const int bnb = b * 32 + nb;
        u16* Op = Opart + ((size_t)(sp * NBLK2 + bnb) * 64) * 128;
        #pragma unroll
        for (int qs = 0; qs < 2; ++qs)
            #pragma unroll
            for (int ct = 0; ct < 4; ++ct) {
                const int c    = ct * 16 + lr;
                const int qloc = wave * 32 + qs * 16 + lg * 4;
                u16 pkk[4];
                #pragma unroll
                for (int r = 0; r < 4; ++r) pkk[r] = f2h(o[qs][ct][r] / lrow[qs][r]);
                *(uint2*)(Op + (size_t)c * 128 + qloc) = *(uint2*)pkk;
            }
        float* Mp = Ml + (size_t)(sp * NBLK2 + bnb) * 256;
        if (lg == 0) {
            Mp[wave * 32 + lr]      = mrow[0];
            Mp[wave * 32 + 16 + lr] = mrow[1];
        }
        if (lr == 0) {
            #pragma unroll
            for (int qs = 0; qs < 2; ++qs)
                #pragma unroll
                for (int r = 0; r < 4; ++r)
                    Mp[128 + wave * 32 + qs * 16 + 4 * lg + r] = lrow[qs][r];
        }
    }
}

// ---------------------------------------------------------------------------
// Combine S partials (normalized fp16 O, log2-domain m), single-pass.
// Grid (NBLK2, 4): each block handles an 8-q slice.
//   out = sum_s (w_s l_s Ohat_s) / sum_s (w_s l_s),  w_s = 2^(m_s - M)
// ---------------------------------------------------------------------------
template<int S>
__global__ __launch_bounds__(256) void combine_kernel(
    const u16* __restrict__ Opart, const float* __restrict__ Ml,
    float* __restrict__ out)
{
    const int bnb = blockIdx.x;           // 0..255
    const int yb  = blockIdx.y;           // 0..3: 8-q slice
    const int b = bnb >> 5, nb = bnb & 31;
    const int tid = threadIdx.x;
    const int c  = tid >> 2;
    const int q0 = (tid & 3) * 32 + yb * 8;

    #pragma unroll
    for (int qq = 0; qq < 8; qq += 4) {
        const int q = q0 + qq;
        f32x4 M = {-1e30f, -1e30f, -1e30f, -1e30f};
        #pragma unroll
        for (int s = 0; s < S; ++s) {
            const float* Mp = Ml + (size_t)(s * NBLK2 + bnb) * 256;
            f32x4 ms = *(const f32x4*)(Mp + q);
            #pragma unroll
            for (int j = 0; j < 4; ++j) M[j] = fmaxf(M[j], ms[j]);
        }
        f32x4 den = {0.f, 0.f, 0.f, 0.f};
        f32x4 acc = {0.f, 0.f, 0.f, 0.f};
        #pragma unroll
        for (int s = 0; s < S; ++s) {
            const float* Mp = Ml + (size_t)(s * NBLK2 + bnb) * 256;
            f32x4 ms = *(const f32x4*)(Mp + q);
            f32x4 ls = *(const f32x4*)(Mp + 128 + q);
            uint2 hv = *(const uint2*)(Opart +
                          ((size_t)(s * NBLK2 + bnb) * 64 + c) * 128 + q);
            u16 h4[4]; __builtin_memcpy(h4, &hv, 8);
            #pragma unroll
            for (int j = 0; j < 4; ++j) {
                float w = ex2(ms[j] - M[j]) * ls[j];
                den[j] += w;
                acc[j] += w * h2f(h4[j]);
            }
        }
        #pragma unroll
        for (int j = 0; j < 4; ++j) acc[j] /= den[j];
        *(f32x4*)(out + (size_t)(b * CC + c) * HW + nb * 128 + q) = acc;
    }
}

extern "C" void kernel_launch(void* const* d_in, const int* in_sizes, int n_in,
                              void* d_out, int out_size, void* d_ws, size_t ws_size,
                              hipStream_t stream)
{
    const float* x  = (const float*)d_in[0];
    const float* wq = (const float*)d_in[1];
    const float* wk = (const float*)d_in[2];
    const float* wv = (const float*)d_in[3];
    u16* ws  = (u16*)d_ws;
    u16* Qr  = ws;                              // [8][4096][32]
    u16* Kf  = ws + (size_t)8 * HW * DQK;       // pre-fragmented K (fp16)
    u16* Vf  = ws + (size_t)16 * HW * DQK;      // pre-fragmented V (bf16)
    u16* Opart = ws + (size_t)4194304;          // after 8MB, fp16 partials
    float* out = (float*)d_out;

    proj_kernel<<<dim3(8, 64), 256, 0, stream>>>(x, wq, wk, wv, Qr, Kf, Vf);

    const size_t qkv_b   = 8ull * 1024 * 1024;
    const size_t opart_b = (size_t)NBLK2 * 64 * 128 * 2;     // per split (fp16)
    const size_t ml_b    = (size_t)NBLK2 * 256 * 4;          // per split

    if (ws_size >= qkv_b + 2 * (opart_b + ml_b)) {
        float* Ml = (float*)(Opart + 2ull * NBLK2 * 64 * 128);
        attn_kernel<2><<<dim3(8, 32, 2), 256, 0, stream>>>(Qr, Kf, Vf, out, Opart, Ml);
        combine_kernel<2><<<dim3(NBLK2, 4), 256, 0, stream>>>(Opart, Ml, out);
    } else {
        attn_kernel<1><<<dim3(8, 32, 1), 256, 0, stream>>>(Qr, Kf, Vf, out, nullptr, nullptr);
    }
}

// Round 22
// 59.493 us; speedup vs baseline: 1.0143x; 1.0143x over previous
//
#include <hip/hip_runtime.h>
#include <hip/hip_fp16.h>

// SAM self-attention. bs=8, C=64, Dqk=32, HW=4096. Inputs f32, output f32.
// fp16 MFMA (f32 accum), KV-split-2 flash attention.
// attn: no LDS / no barriers; pre-fragmented Kf/Vf global loads (L1/L2-hot).
// FINAL (r22 = r19/r17, best measured 59.6us):
//  - r21 lesson: f2bf (RNE rounding = 4-op chain/elem) is slower than the
//    defer-max branch it replaced; cvt_pkrtz fp16 pack is the right tool.
//  - r13/r14: never thread state through MFMA C across iterations.
//  - r18: never pass register arrays by reference (scratch spill).
//  - S=2 matches measured ~2-block/CU residency; S-invariant core throughput.

typedef short          f16x8 __attribute__((ext_vector_type(8)));
typedef float          f32x4 __attribute__((ext_vector_type(4)));
typedef unsigned short u16;
typedef unsigned int   u32;

#define HW  4096
#define CC  64
#define DQK 32
#define NBLK2 256     // 8 batches * 32 q-blocks (128 q each)
#define THR2 11.54f   // defer-max threshold (log2 domain): P <= 2^11.54 ~ e^8

__device__ __forceinline__ u16 f2h(float f) {
    __half h = __float2half(f);
    return *reinterpret_cast<u16*>(&h);
}
__device__ __forceinline__ float h2f(u16 u) {
    __half h; __builtin_memcpy(&h, &u, 2); return __half2float(h);
}
__device__ __forceinline__ u32 pk2(float a, float b) {
    auto r = __builtin_amdgcn_cvt_pkrtz(a, b);
    u32 u; __builtin_memcpy(&u, &r, 4); return u;
}
__device__ __forceinline__ float ex2(float x) {
    return __builtin_amdgcn_exp2f(x);
}
// max16 (fmax chain; clang fuses to v_max3)
__device__ __forceinline__ float max16(const f32x4* s) {
    float a = fmaxf(fmaxf(s[0][0], s[0][1]), s[0][2]);
    a = fmaxf(fmaxf(a, s[0][3]), s[1][0]);
    a = fmaxf(fmaxf(a, s[1][1]), s[1][2]);
    a = fmaxf(fmaxf(a, s[1][3]), s[2][0]);
    a = fmaxf(fmaxf(a, s[2][1]), s[2][2]);
    a = fmaxf(fmaxf(a, s[2][3]), s[3][0]);
    a = fmaxf(fmaxf(a, s[3][1]), s[3][2]);
    return fmaxf(a, s[3][3]);
}

// ---------------------------------------------------------------------------
// Projection. Q -> Qr[n][32]; K -> Kf pre-fragmented (uint2 stores);
// V -> Vf pre-fragmented via SWAPPED mfma (D[m][c]) -> uint2 stores.
// wq pre-scaled by log2(e) -> exp2-domain scores.
// ---------------------------------------------------------------------------
__global__ __launch_bounds__(256) void proj_kernel(
    const float* __restrict__ x,  const float* __restrict__ wq,
    const float* __restrict__ wk, const float* __restrict__ wv,
    u16* __restrict__ Qr, u16* __restrict__ Kf, u16* __restrict__ Vf)
{
    const int b    = blockIdx.x;
    const int tile = blockIdx.y;          // 64-column chunk index
    const int n0   = tile * 64;
    const int tid  = threadIdx.x;

    __shared__ __align__(16) u16 Xt[64][88];   // X^T tile [n][c]

    {
        const int c  = tid >> 2;
        const int nc = (tid & 3) * 16;
        const float* src = x + ((size_t)(b * CC + c) * HW + n0 + nc);
        float fv[16];
        *(f32x4*)(fv)      = *(const f32x4*)(src);
        *(f32x4*)(fv + 4)  = *(const f32x4*)(src + 4);
        *(f32x4*)(fv + 8)  = *(const f32x4*)(src + 8);
        *(f32x4*)(fv + 12) = *(const f32x4*)(src + 12);
        #pragma unroll
        for (int i = 0; i < 16; ++i) Xt[nc + i][c] = f2h(fv[i]);
    }
    __syncthreads();

    const int wave = tid >> 6;
    const int lane = tid & 63;
    const int lr   = lane & 15;
    const int lg   = lane >> 4;
    const int lk   = lg * 8;

    const float* W = (wave == 0) ? wq : (wave == 1) ? wk
                   : (wave == 2) ? wv : (wv + 32 * 64);
    const float scale = (wave == 0) ? 1.4426950408889634f : 1.0f;   // log2(e)

    f16x8 a[2][2];
    #pragma unroll
    for (int dt = 0; dt < 2; ++dt)
        #pragma unroll
        for (int h = 0; h < 2; ++h) {
            const float* p = W + (dt * 16 + lr) * 64 + h * 32 + lk;
            f32x4 lo = *(const f32x4*)p, hi = *(const f32x4*)(p + 4);
            u16 t[8];
            #pragma unroll
            for (int j = 0; j < 4; ++j) {
                t[j]     = f2h(lo[j] * scale);
                t[4 + j] = f2h(hi[j] * scale);
            }
            a[dt][h] = *(const f16x8*)t;
        }

    const f32x4 fz = {0.f, 0.f, 0.f, 0.f};
    f32x4 acc[2][4];
    #pragma unroll
    for (int dt = 0; dt < 2; ++dt)
        #pragma unroll
        for (int nt = 0; nt < 4; ++nt) acc[dt][nt] = fz;

    if (wave < 2) {
        // D[d][n]: col(lr)=n', row(4lg+r)=d'
        #pragma unroll
        for (int nt = 0; nt < 4; ++nt)
            #pragma unroll
            for (int h = 0; h < 2; ++h) {
                f16x8 bx = *(const f16x8*)(&Xt[nt * 16 + lr][h * 32 + lk]);
                #pragma unroll
                for (int dt = 0; dt < 2; ++dt)
                    acc[dt][nt] = __builtin_amdgcn_mfma_f32_16x16x32_f16(
                                      a[dt][h], bx, acc[dt][nt], 0, 0, 0);
            }
        if (wave == 0) {
            #pragma unroll
            for (int dt = 0; dt < 2; ++dt)
                #pragma unroll
                for (int nt = 0; nt < 4; ++nt) {
                    const int n = n0 + nt * 16 + lr;
                    const int d = dt * 16 + lg * 4;
                    u16 pkk[4];
                    #pragma unroll
                    for (int r = 0; r < 4; ++r) pkk[r] = f2h(acc[dt][nt][r]);
                    *(uint2*)(Qr + ((size_t)(b * HW + n) * DQK + d)) = *(uint2*)pkk;
                }
        } else {
            // K -> Kf: element (m_in, d) at [mt][lgk=d>>3][lrk][j=d&7]
            #pragma unroll
            for (int dt = 0; dt < 2; ++dt)
                #pragma unroll
                for (int nt = 0; nt < 4; ++nt) {
                    const int m_in = nt * 16 + lr;
                    const int mt   = 2 * (m_in >> 5) + ((m_in >> 2) & 1);
                    const int lrk  = ((m_in >> 4) & 1) * 8 + ((m_in >> 3) & 1) * 4 + (m_in & 3);
                    const int lgk  = dt * 2 + (lg >> 1);
                    const int j0   = (lg & 1) * 4;
                    u16 pkk[4];
                    #pragma unroll
                    for (int r = 0; r < 4; ++r) pkk[r] = f2h(acc[dt][nt][r]);
                    *(uint2*)(Kf + (size_t)(b * 64 + tile) * 2048
                                 + mt * 512 + lgk * 128 + lrk * 8 + j0) = *(uint2*)pkk;
                }
        }
    } else {
        // V waves: SWAPPED mfma -> D[m][c]: col(lr)=c', row(4lg+r)=m'
        #pragma unroll
        for (int nt = 0; nt < 4; ++nt)
            #pragma unroll
            for (int h = 0; h < 2; ++h) {
                f16x8 bx = *(const f16x8*)(&Xt[nt * 16 + lr][h * 32 + lk]);
                #pragma unroll
                for (int dt = 0; dt < 2; ++dt)
                    acc[dt][nt] = __builtin_amdgcn_mfma_f32_16x16x32_f16(
                                      bx, a[dt][h], acc[dt][nt], 0, 0, 0);
            }
        const int cbase = (wave - 2) * 32;
        #pragma unroll
        for (int dt = 0; dt < 2; ++dt)
            #pragma unroll
            for (int nt = 0; nt < 4; ++nt) {
                const int c   = cbase + dt * 16 + lr;
                const int ct  = c >> 4, lrv = c & 15;
                const int m0  = nt * 16 + 4 * lg;          // r = 0..3 consecutive
                const int h   = m0 >> 5;
                const int lgv = (m0 >> 3) & 3;
                const int j0  = m0 & 7;                    // (lg&1)*4
                u16 pkk[4];
                #pragma unroll
                for (int r = 0; r < 4; ++r) pkk[r] = f2h(acc[dt][nt][r]);
                *(uint2*)(Vf + (size_t)(b * 64 + tile) * 4096
                             + ct * 1024 + h * 512 + lgv * 128 + lrv * 8 + j0)
                    = *(uint2*)pkk;
            }
    }
}

// ---------------------------------------------------------------------------
// Flash attention, KV-split S ways. Block = 128 q (4 independent waves x 32).
// EXACT r11 schedule: C=0 QK MFMA, rs=mfma(C=0)+VALU lrow fold, no LDS,
// hot loop fully inline.
// ---------------------------------------------------------------------------
template<int S>
__global__ __launch_bounds__(256, 4) void attn_kernel(
    const u16* __restrict__ Qr, const u16* __restrict__ Kf,
    const u16* __restrict__ Vf, float* __restrict__ out,
    u16* __restrict__ Opart, float* __restrict__ Ml)
{
    constexpr int NT = HW / S / 64;
    const int b    = blockIdx.x;
    const int nb   = blockIdx.y;
    const int sp   = blockIdx.z;
    const int tid  = threadIdx.x;
    const int wave = tid >> 6;
    const int lane = tid & 63;
    const int lr   = lane & 15;
    const int lg   = lane >> 4;
    const int lk   = lg * 8;

    const int qb = nb * 128 + wave * 32;
    const f16x8 aq0 = *(const f16x8*)(Qr + (size_t)(b * HW + qb + lr) * DQK + lk);
    const f16x8 aq1 = *(const f16x8*)(Qr + (size_t)(b * HW + qb + 16 + lr) * DQK + lk);

    const f16x8 ones = { 0x3C00, 0x3C00, 0x3C00, 0x3C00,
                         0x3C00, 0x3C00, 0x3C00, 0x3C00 };
    const f32x4 fz = {0.f, 0.f, 0.f, 0.f};

    const int tile0 = sp * NT;
    const u16* KfT = Kf + (size_t)(b * 64 + tile0) * 2048 + lg * 128 + lr * 8;
    const u16* VfT = Vf + (size_t)(b * 64 + tile0) * 4096 + lg * 128 + lr * 8;

    f16x8 kf[4], vf[4][2];
    #pragma unroll
    for (int mt = 0; mt < 4; ++mt)
        kf[mt] = *(const f16x8*)(KfT + mt * 512);
    #pragma unroll
    for (int ct = 0; ct < 4; ++ct)
        #pragma unroll
        for (int h = 0; h < 2; ++h)
            vf[ct][h] = *(const f16x8*)(VfT + ct * 1024 + h * 512);

    f32x4 o[2][4];
    #pragma unroll
    for (int qs = 0; qs < 2; ++qs)
        #pragma unroll
        for (int ct = 0; ct < 4; ++ct) o[qs][ct] = fz;
    f32x4 lrow[2] = {fz, fz};                 // q = 4*lg + r (o-layout)
    float mrow[2] = {-1e30f, -1e30f};         // q = lr      (s-layout)

    #pragma unroll 2
    for (int t = 0; t < NT; ++t) {
        const int tn = (t + 1 < NT) ? t + 1 : t;

        // ================= qs = 0 =================
        f32x4 s[4];
        #pragma unroll
        for (int mt = 0; mt < 4; ++mt)
            s[mt] = __builtin_amdgcn_mfma_f32_16x16x32_f16(kf[mt], aq0, fz, 0, 0, 0);

        float lm = max16(s);
        if (__any(lm > mrow[0] + THR2)) {
            float v = lm;
            v = fmaxf(v, __shfl_xor(v, 16, 64));
            v = fmaxf(v, __shfl_xor(v, 32, 64));
            float mnew  = fmaxf(mrow[0], v);
            float alpha = ex2(mrow[0] - mnew);
            mrow[0] = mnew;
            f32x4 al;
            #pragma unroll
            for (int r = 0; r < 4; ++r) al[r] = __shfl(alpha, 4 * lg + r, 64);
            #pragma unroll
            for (int ct = 0; ct < 4; ++ct)
                #pragma unroll
                for (int r = 0; r < 4; ++r) o[0][ct][r] *= al[r];
            #pragma unroll
            for (int r = 0; r < 4; ++r) lrow[0][r] *= al[r];
        }
        f16x8 pa0[2];
        {
            const float m = mrow[0];
            #pragma unroll
            for (int h = 0; h < 2; ++h) {
                u32 w[4];
                w[0] = pk2(ex2(s[2*h][0] - m), ex2(s[2*h][1] - m));
                w[1] = pk2(ex2(s[2*h][2] - m), ex2(s[2*h][3] - m));
                w[2] = pk2(ex2(s[2*h+1][0] - m), ex2(s[2*h+1][1] - m));
                w[3] = pk2(ex2(s[2*h+1][2] - m), ex2(s[2*h+1][3] - m));
                __builtin_memcpy(&pa0[h], w, 16);
            }
        }
        {
            f32x4 rs = __builtin_amdgcn_mfma_f32_16x16x32_f16(pa0[0], ones, fz, 0, 0, 0);
            rs = __builtin_amdgcn_mfma_f32_16x16x32_f16(pa0[1], ones, rs, 0, 0, 0);
            #pragma unroll
            for (int r = 0; r < 4; ++r) lrow[0][r] += rs[r];
        }
        #pragma unroll
        for (int ct = 0; ct < 4; ++ct) {
            o[0][ct] = __builtin_amdgcn_mfma_f32_16x16x32_f16(pa0[0], vf[ct][0], o[0][ct], 0, 0, 0);
            o[0][ct] = __builtin_amdgcn_mfma_f32_16x16x32_f16(pa0[1], vf[ct][1], o[0][ct], 0, 0, 0);
        }

        // ================= qs = 1 =================
        #pragma unroll
        for (int mt = 0; mt < 4; ++mt)
            s[mt] = __builtin_amdgcn_mfma_f32_16x16x32_f16(kf[mt], aq1, fz, 0, 0, 0);

        // kf consumed -> reload for next tile (hides under softmax+PV)
        #pragma unroll
        for (int mt = 0; mt < 4; ++mt)
            kf[mt] = *(const f16x8*)(KfT + (size_t)tn * 2048 + mt * 512);

        lm = max16(s);
        if (__any(lm > mrow[1] + THR2)) {
            float v = lm;
            v = fmaxf(v, __shfl_xor(v, 16, 64));
            v = fmaxf(v, __shfl_xor(v, 32, 64));
            float mnew  = fmaxf(mrow[1], v);
            float alpha = ex2(mrow[1] - mnew);
            mrow[1] = mnew;
            f32x4 al;
            #pragma unroll
            for (int r = 0; r < 4; ++r) al[r] = __shfl(alpha, 4 * lg + r, 64);
            #pragma unroll
            for (int ct = 0; ct < 4; ++ct)
                #pragma unroll
                for (int r = 0; r < 4; ++r) o[1][ct][r] *= al[r];
            #pragma unroll
            for (int r = 0; r < 4; ++r) lrow[1][r] *= al[r];
        }
        f16x8 pa1[2];
        {
            const float m = mrow[1];
            #pragma unroll
            for (int h = 0; h < 2; ++h) {
                u32 w[4];
                w[0] = pk2(ex2(s[2*h][0] - m), ex2(s[2*h][1] - m));
                w[1] = pk2(ex2(s[2*h][2] - m), ex2(s[2*h][3] - m));
                w[2] = pk2(ex2(s[2*h+1][0] - m), ex2(s[2*h+1][1] - m));
                w[3] = pk2(ex2(s[2*h+1][2] - m), ex2(s[2*h+1][3] - m));
                __builtin_memcpy(&pa1[h], w, 16);
            }
        }
        {
            f32x4 rs = __builtin_amdgcn_mfma_f32_16x16x32_f16(pa1[0], ones, fz, 0, 0, 0);
            rs = __builtin_amdgcn_mfma_f32_16x16x32_f16(pa1[1], ones, rs, 0, 0, 0);
            #pragma unroll
            for (int r = 0; r < 4; ++r) lrow[1][r] += rs[r];
        }
        #pragma unroll
        for (int ct = 0; ct < 4; ++ct) {
            o[1][ct] = __builtin_amdgcn_mfma_f32_16x16x32_f16(pa1[0], vf[ct][0], o[1][ct], 0, 0, 0);
            o[1][ct] = __builtin_amdgcn_mfma_f32_16x16x32_f16(pa1[1], vf[ct][1], o[1][ct], 0, 0, 0);
        }

        // vf consumed -> reload for next tile (hides under next QK+softmax)
        #pragma unroll
        for (int ct = 0; ct < 4; ++ct)
            #pragma unroll
            for (int h = 0; h < 2; ++h)
                vf[ct][h] = *(const f16x8*)(VfT + (size_t)tn * 4096 + ct * 1024 + h * 512);
    }

    if constexpr (S == 1) {
        #pragma unroll
        for (int qs = 0; qs < 2; ++qs)
            #pragma unroll
            for (int ct = 0; ct < 4; ++ct) {
                const int c = ct * 16 + lr;
                f32x4 st;
                #pragma unroll
                for (int r = 0; r < 4; ++r) st[r] = o[qs][ct][r] / lrow[qs][r];
                *(f32x4*)(out + (size_t)(b * CC + c) * HW + qb + qs * 16 + lg * 4) = st;
            }
    } else {
        const int bnb = b * 32 + nb;
        u16* Op = Opart + ((size_t)(sp * NBLK2 + bnb) * 64) * 128;
        #pragma unroll
        for (int qs = 0; qs < 2; ++qs)
            #pragma unroll
            for (int ct = 0; ct < 4; ++ct) {
                const int c    = ct * 16 + lr;
                const int qloc = wave * 32 + qs * 16 + lg * 4;
                u16 pkk[4];
                #pragma unroll
                for (int r = 0; r < 4; ++r) pkk[r] = f2h(o[qs][ct][r] / lrow[qs][r]);
                *(uint2*)(Op + (size_t)c * 128 + qloc) = *(uint2*)pkk;
            }
        float* Mp = Ml + (size_t)(sp * NBLK2 + bnb) * 256;
        if (lg == 0) {
            Mp[wave * 32 + lr]      = mrow[0];
            Mp[wave * 32 + 16 + lr] = mrow[1];
        }
        if (lr == 0) {
            #pragma unroll
            for (int qs = 0; qs < 2; ++qs)
                #pragma unroll
                for (int r = 0; r < 4; ++r)
                    Mp[128 + wave * 32 + qs * 16 + 4 * lg + r] = lrow[qs][r];
        }
    }
}

// ---------------------------------------------------------------------------
// Combine S partials (normalized fp16 O, log2-domain m), single-pass.
// Grid (NBLK2, 4): each block handles an 8-q slice.
//   out = sum_s (w_s l_s Ohat_s) / sum_s (w_s l_s),  w_s = 2^(m_s - M)
// ---------------------------------------------------------------------------
template<int S>
__global__ __launch_bounds__(256) void combine_kernel(
    const u16* __restrict__ Opart, const float* __restrict__ Ml,
    float* __restrict__ out)
{
    const int bnb = blockIdx.x;           // 0..255
    const int yb  = blockIdx.y;           // 0..3: 8-q slice
    const int b = bnb >> 5, nb = bnb & 31;
    const int tid = threadIdx.x;
    const int c  = tid >> 2;
    const int q0 = (tid & 3) * 32 + yb * 8;

    #pragma unroll
    for (int qq = 0; qq < 8; qq += 4) {
        const int q = q0 + qq;
        f32x4 M = {-1e30f, -1e30f, -1e30f, -1e30f};
        #pragma unroll
        for (int s = 0; s < S; ++s) {
            const float* Mp = Ml + (size_t)(s * NBLK2 + bnb) * 256;
            f32x4 ms = *(const f32x4*)(Mp + q);
            #pragma unroll
            for (int j = 0; j < 4; ++j) M[j] = fmaxf(M[j], ms[j]);
        }
        f32x4 den = {0.f, 0.f, 0.f, 0.f};
        f32x4 acc = {0.f, 0.f, 0.f, 0.f};
        #pragma unroll
        for (int s = 0; s < S; ++s) {
            const float* Mp = Ml + (size_t)(s * NBLK2 + bnb) * 256;
            f32x4 ms = *(const f32x4*)(Mp + q);
            f32x4 ls = *(const f32x4*)(Mp + 128 + q);
            uint2 hv = *(const uint2*)(Opart +
                          ((size_t)(s * NBLK2 + bnb) * 64 + c) * 128 + q);
            u16 h4[4]; __builtin_memcpy(h4, &hv, 8);
            #pragma unroll
            for (int j = 0; j < 4; ++j) {
                float w = ex2(ms[j] - M[j]) * ls[j];
                den[j] += w;
                acc[j] += w * h2f(h4[j]);
            }
        }
        #pragma unroll
        for (int j = 0; j < 4; ++j) acc[j] /= den[j];
        *(f32x4*)(out + (size_t)(b * CC + c) * HW + nb * 128 + q) = acc;
    }
}

extern "C" void kernel_launch(void* const* d_in, const int* in_sizes, int n_in,
                              void* d_out, int out_size, void* d_ws, size_t ws_size,
                              hipStream_t stream)
{
    const float* x  = (const float*)d_in[0];
    const float* wq = (const float*)d_in[1];
    const float* wk = (const float*)d_in[2];
    const float* wv = (const float*)d_in[3];
    u16* ws  = (u16*)d_ws;
    u16* Qr  = ws;                              // [8][4096][32]
    u16* Kf  = ws + (size_t)8 * HW * DQK;       // pre-fragmented K
    u16* Vf  = ws + (size_t)16 * HW * DQK;      // pre-fragmented V
    u16* Opart = ws + (size_t)4194304;          // after 8MB, fp16 partials
    float* out = (float*)d_out;

    proj_kernel<<<dim3(8, 64), 256, 0, stream>>>(x, wq, wk, wv, Qr, Kf, Vf);

    const size_t qkv_b   = 8ull * 1024 * 1024;
    const size_t opart_b = (size_t)NBLK2 * 64 * 128 * 2;     // per split (fp16)
    const size_t ml_b    = (size_t)NBLK2 * 256 * 4;          // per split

    if (ws_size >= qkv_b + 2 * (opart_b + ml_b)) {
        // S=2: 512 blocks = 2 blocks/CU, matching measured residency cap
        float* Ml = (float*)(Opart + 2ull * NBLK2 * 64 * 128);
        attn_kernel<2><<<dim3(8, 32, 2), 256, 0, stream>>>(Qr, Kf, Vf, out, Opart, Ml);
        combine_kernel<2><<<dim3(NBLK2, 4), 256, 0, stream>>>(Opart, Ml, out);
    } else {
        attn_kernel<1><<<dim3(8, 32, 1), 256, 0, stream>>>(Qr, Kf, Vf, out, nullptr, nullptr);
    }
}